// Round 1
// baseline (2551.124 us; speedup 1.0000x reference)
//
#include <hip/hip_runtime.h>
#include <cstdint>
#include <cstddef>

typedef __bf16 bf16;
typedef __attribute__((ext_vector_type(8))) __bf16 bf16x8;
typedef __attribute__((ext_vector_type(4))) float floatx4;

#define AS1 __attribute__((address_space(1)))
#define AS3 __attribute__((address_space(3)))
#define GLD16(g, l) __builtin_amdgcn_global_load_lds((const AS1 void*)(g), (AS3 void*)(l), 16, 0, 0)

static constexpr int S_ = 2048, H_ = 2048, NH_ = 16, HD_ = 128, FF_ = 8192, V_ = 32000, TH_ = 6144;

// ---------------- embedding gather ----------------
__global__ __launch_bounds__(256) void embed_k(const int* __restrict__ x,
                                               const float* __restrict__ embed,
                                               float* __restrict__ h) {
  int s = blockIdx.x;
  int row = x[s];
  const float4* src = (const float4*)(embed + (size_t)row * H_);
  float4* dst = (float4*)(h + (size_t)s * H_);
  for (int i = threadIdx.x; i < H_ / 4; i += 256) dst[i] = src[i];
}

// ---------------- layernorm (fp32 in, bf16 out) ----------------
__global__ __launch_bounds__(256) void ln_k(const float* __restrict__ x,
                                            const float* __restrict__ g,
                                            const float* __restrict__ b,
                                            bf16* __restrict__ out) {
  int row = blockIdx.x;
  int tid = threadIdx.x;
  const float* xr = x + (size_t)row * H_;
  float v[8];
  float s = 0.f;
#pragma unroll
  for (int i = 0; i < 8; i++) { v[i] = xr[i * 256 + tid]; s += v[i]; }
#pragma unroll
  for (int off = 32; off; off >>= 1) s += __shfl_xor(s, off, 64);
  __shared__ float r1[4], r2[4];
  int wave = tid >> 6, lane = tid & 63;
  if (!lane) r1[wave] = s;
  __syncthreads();
  float mean = (r1[0] + r1[1] + r1[2] + r1[3]) * (1.f / H_);
  float q = 0.f;
#pragma unroll
  for (int i = 0; i < 8; i++) { float d = v[i] - mean; q += d * d; }
#pragma unroll
  for (int off = 32; off; off >>= 1) q += __shfl_xor(q, off, 64);
  if (!lane) r2[wave] = q;
  __syncthreads();
  float var = (r2[0] + r2[1] + r2[2] + r2[3]) * (1.f / H_);
  float inv = rsqrtf(var + 1e-5f);
  bf16* orow = out + (size_t)row * H_;
#pragma unroll
  for (int i = 0; i < 8; i++) {
    int c = i * 256 + tid;
    orow[c] = (bf16)((v[i] - mean) * inv * g[c] + b[c]);
  }
}

// ---------------- fp32 W[K][N] -> bf16 Wt[N][K] (transpose+convert) ----------------
__global__ __launch_bounds__(256) void convT_k(const float* __restrict__ W,
                                               bf16* __restrict__ Wt,
                                               int ldw, int ldwt) {
  __shared__ float t[32][33];
  int n0 = blockIdx.x * 32, k0 = blockIdx.y * 32;
  int tx = threadIdx.x & 31, ty = threadIdx.x >> 5;
#pragma unroll
  for (int i = 0; i < 4; i++)
    t[ty + 8 * i][tx] = W[(size_t)(k0 + ty + 8 * i) * ldw + n0 + tx];
  __syncthreads();
#pragma unroll
  for (int i = 0; i < 4; i++)
    Wt[(size_t)(n0 + ty + 8 * i) * ldwt + k0 + tx] = (bf16)t[tx][ty + 8 * i];
}

// ---------------- GEMM: C[M][N] = A[M][K](bf16) x Bt[N][K](bf16) + bias ----------------
// m97 structure: 128x128 tile, BK=32, 4 waves 2x2, global_load_lds width 16.
__global__ __launch_bounds__(256) void gemm_bt(const bf16* __restrict__ A,
                                               const bf16* __restrict__ Bt,
                                               const float* __restrict__ bias,
                                               float* __restrict__ C,
                                               int K, int ldc) {
  __shared__ __align__(16) bf16 As_[128 * 32];
  __shared__ __align__(16) bf16 Bs_[128 * 32];
  const int tid = threadIdx.x;
  const int wave = tid >> 6, lane = tid & 63;
  const int quad = lane >> 4, l16 = lane & 15;
  const int m0 = blockIdx.y * 128, n0 = blockIdx.x * 128;
  const int wm = (wave >> 1) * 64, wn = (wave & 1) * 64;
  const bf16* Ag = A + (size_t)(m0 + (tid >> 2)) * K + (tid & 3) * 8;
  const bf16* Bg = Bt + (size_t)(n0 + (tid >> 2)) * K + (tid & 3) * 8;
  bf16* AsW = As_ + wave * 512;  // wave-uniform LDS base; HW adds lane*16B
  bf16* BsW = Bs_ + wave * 512;
  floatx4 acc[4][4] = {};
  for (int k0 = 0; k0 < K; k0 += 32) {
    GLD16(Ag, AsW);
    GLD16(Ag + (size_t)64 * K, AsW + 2048);
    GLD16(Bg, BsW);
    GLD16(Bg + (size_t)64 * K, BsW + 2048);
    Ag += 32; Bg += 32;
    __syncthreads();
    bf16x8 af[4], bfr[4];
#pragma unroll
    for (int i = 0; i < 4; i++)
      af[i] = *(const bf16x8*)(As_ + (wm + i * 16 + l16) * 32 + quad * 8);
#pragma unroll
    for (int j = 0; j < 4; j++)
      bfr[j] = *(const bf16x8*)(Bs_ + (wn + j * 16 + l16) * 32 + quad * 8);
#pragma unroll
    for (int i = 0; i < 4; i++)
#pragma unroll
      for (int j = 0; j < 4; j++)
        acc[i][j] = __builtin_amdgcn_mfma_f32_16x16x32_bf16(af[i], bfr[j], acc[i][j], 0, 0, 0);
    __syncthreads();
  }
#pragma unroll
  for (int i = 0; i < 4; i++) {
    int row = m0 + wm + i * 16 + quad * 4;
#pragma unroll
    for (int j = 0; j < 4; j++) {
      int col = n0 + wn + j * 16 + l16;
      float bb = bias ? bias[col] : 0.f;
#pragma unroll
      for (int r = 0; r < 4; r++)
        C[(size_t)(row + r) * ldc + col] = acc[i][j][r] + bb;
    }
  }
}

// ---------------- RoPE in-place on qkv fp32 [S][NH][3*HD] ----------------
__global__ __launch_bounds__(256) void rope_k(float* __restrict__ qkv) {
  int idx = blockIdx.x * 256 + threadIdx.x;
  int j = idx & 15, n = (idx >> 4) & 15, s = idx >> 8;
  float ang = (float)s * powf(10000.f, -(float)j * (1.f / 16.f));
  float c = cosf(ang), si = sinf(ang);
  float* base = qkv + (size_t)s * TH_ + n * 384;
  float x0 = base[j], x1 = base[j + 16];
  base[j] = x0 * c - x1 * si;
  base[j + 16] = x1 * c + x0 * si;
  float* kb = base + 128;
  x0 = kb[j]; x1 = kb[j + 16];
  kb[j] = x0 * c - x1 * si;
  kb[j + 16] = x1 * c + x0 * si;
}

// ---------------- MFMA flash attention (causal), ctx out in bf16 [S][H] ----------------
__global__ __launch_bounds__(256) void fattn_k(const float* __restrict__ qkv,
                                               bf16* __restrict__ ctx) {
  const int bx = blockIdx.x;
  const int n = bx & 15;
  const int qt = (gridDim.x >> 4) - 1 - (bx >> 4);  // heavy blocks first
  const int q0 = qt * 64;
  __shared__ __align__(16) bf16 q_lds[64][136];
  __shared__ __align__(16) bf16 k_lds[32][136];
  __shared__ __align__(16) bf16 v_lds[128][40];   // transposed: [dim][key]
  __shared__ __align__(16) bf16 p_lds[4][16][40]; // per-wave P round-trip
  const int tid = threadIdx.x;
  const int wave = tid >> 6, lane = tid & 63;
  const int quad = lane >> 4, l16 = lane & 15;
  // stage Q tile (64 rows x 128 dims), convert to bf16
  {
    int r = tid >> 2, c0 = (tid & 3) * 32;
    const float4* src = (const float4*)(qkv + (size_t)(q0 + r) * TH_ + n * 384 + c0);
#pragma unroll
    for (int c = 0; c < 8; c++) {
      float4 f = src[c];
      q_lds[r][c0 + 4 * c + 0] = (bf16)f.x;
      q_lds[r][c0 + 4 * c + 1] = (bf16)f.y;
      q_lds[r][c0 + 4 * c + 2] = (bf16)f.z;
      q_lds[r][c0 + 4 * c + 3] = (bf16)f.w;
    }
  }
  floatx4 o_acc[8] = {};
  float m_r[4], l_r[4];
#pragma unroll
  for (int r = 0; r < 4; r++) { m_r[r] = -1e30f; l_r[r] = 0.f; }
  const int nkt = q0 / 32 + 2;
  for (int kt = 0; kt < nkt; kt++) {
    __syncthreads();
    {
      int r = tid >> 3, c0 = (tid & 7) * 16;
      const float4* ks = (const float4*)(qkv + (size_t)(kt * 32 + r) * TH_ + n * 384 + 128 + c0);
      const float4* vs = (const float4*)(qkv + (size_t)(kt * 32 + r) * TH_ + n * 384 + 256 + c0);
#pragma unroll
      for (int c = 0; c < 4; c++) {
        float4 f = ks[c];
        k_lds[r][c0 + 4 * c + 0] = (bf16)f.x;
        k_lds[r][c0 + 4 * c + 1] = (bf16)f.y;
        k_lds[r][c0 + 4 * c + 2] = (bf16)f.z;
        k_lds[r][c0 + 4 * c + 3] = (bf16)f.w;
        float4 g = vs[c];
        v_lds[c0 + 4 * c + 0][r] = (bf16)g.x;
        v_lds[c0 + 4 * c + 1][r] = (bf16)g.y;
        v_lds[c0 + 4 * c + 2][r] = (bf16)g.z;
        v_lds[c0 + 4 * c + 3][r] = (bf16)g.w;
      }
    }
    __syncthreads();
    // S = Q(16x128) @ K^T(128x32) per wave
    floatx4 s0 = {}, s1 = {};
#pragma unroll
    for (int ks_ = 0; ks_ < 4; ks_++) {
      bf16x8 aq = *(const bf16x8*)&q_lds[wave * 16 + l16][ks_ * 32 + quad * 8];
      bf16x8 b0 = *(const bf16x8*)&k_lds[l16][ks_ * 32 + quad * 8];
      bf16x8 b1 = *(const bf16x8*)&k_lds[16 + l16][ks_ * 32 + quad * 8];
      s0 = __builtin_amdgcn_mfma_f32_16x16x32_bf16(aq, b0, s0, 0, 0, 0);
      s1 = __builtin_amdgcn_mfma_f32_16x16x32_bf16(aq, b1, s1, 0, 0, 0);
    }
    const float scale = 0.08838834764831845f;  // 1/sqrt(128)
#pragma unroll
    for (int r = 0; r < 4; r++) {
      int qg = q0 + wave * 16 + quad * 4 + r;
      int j0 = kt * 32 + l16;
      float sv0 = (j0 <= qg) ? s0[r] * scale : -1e30f;
      float sv1 = (j0 + 16 <= qg) ? s1[r] * scale : -1e30f;
      float mx = fmaxf(sv0, sv1);
#pragma unroll
      for (int off = 1; off < 16; off <<= 1) mx = fmaxf(mx, __shfl_xor(mx, off, 64));
      float mnew = fmaxf(m_r[r], mx);
      float p0 = __expf(sv0 - mnew);
      float p1 = __expf(sv1 - mnew);
      float ps = p0 + p1;
#pragma unroll
      for (int off = 1; off < 16; off <<= 1) ps += __shfl_xor(ps, off, 64);
      float alpha = __expf(m_r[r] - mnew);
      l_r[r] = l_r[r] * alpha + ps;
      m_r[r] = mnew;
#pragma unroll
      for (int dt = 0; dt < 8; dt++) o_acc[dt][r] *= alpha;
      p_lds[wave][quad * 4 + r][l16] = (bf16)p0;
      p_lds[wave][quad * 4 + r][16 + l16] = (bf16)p1;
    }
    __syncthreads();  // safety: P visibility before A-layout re-read
    // O += P(16x32) @ V(32x128)
    bf16x8 ap = *(const bf16x8*)&p_lds[wave][l16][quad * 8];
#pragma unroll
    for (int dt = 0; dt < 8; dt++) {
      bf16x8 bv = *(const bf16x8*)&v_lds[dt * 16 + l16][quad * 8];
      o_acc[dt] = __builtin_amdgcn_mfma_f32_16x16x32_bf16(ap, bv, o_acc[dt], 0, 0, 0);
    }
  }
#pragma unroll
  for (int dt = 0; dt < 8; dt++) {
#pragma unroll
    for (int r = 0; r < 4; r++) {
      int qg = q0 + wave * 16 + quad * 4 + r;
      ctx[(size_t)qg * H_ + n * HD_ + dt * 16 + l16] = (bf16)(o_acc[dt][r] / l_r[r]);
    }
  }
}

// ---------------- GELU (fp32 in, bf16 out) ----------------
__global__ __launch_bounds__(256) void gelu_k(const float* __restrict__ mid,
                                              bf16* __restrict__ out) {
  int idx = blockIdx.x * 256 + threadIdx.x;
  float4 v = ((const float4*)mid)[idx];
  float r[4] = {v.x, v.y, v.z, v.w};
#pragma unroll
  for (int i = 0; i < 4; i++) {
    float x = r[i];
    float t = tanhf(0.79788456f * x * (1.f + 0.044715f * x * x));
    r[i] = 0.5f * x * (1.f + t);
  }
  bf16* o = out + (size_t)idx * 4;
#pragma unroll
  for (int i = 0; i < 4; i++) o[i] = (bf16)r[i];
}

// ---------------- residual: h += a + m ----------------
__global__ __launch_bounds__(256) void resid_k(float* __restrict__ h,
                                               const float* __restrict__ a,
                                               const float* __restrict__ m) {
  int idx = blockIdx.x * 256 + threadIdx.x;
  float4 hv = ((const float4*)h)[idx];
  float4 av = ((const float4*)a)[idx];
  float4 mv = ((const float4*)m)[idx];
  hv.x += av.x + mv.x;
  hv.y += av.y + mv.y;
  hv.z += av.z + mv.z;
  hv.w += av.w + mv.w;
  ((float4*)h)[idx] = hv;
}

extern "C" void kernel_launch(void* const* d_in, const int* in_sizes, int n_in,
                              void* d_out, int out_size, void* d_ws, size_t ws_size,
                              hipStream_t stream) {
  const int*   x        = (const int*)d_in[0];
  const float* embed    = (const float*)d_in[1];
  const float* ln1_g    = (const float*)d_in[2];
  const float* ln1_b    = (const float*)d_in[3];
  const float* ln2_g    = (const float*)d_in[4];
  const float* ln2_b    = (const float*)d_in[5];
  const float* qkv_w    = (const float*)d_in[6];
  const float* qkv_b    = (const float*)d_in[7];
  const float* dense_w  = (const float*)d_in[8];
  const float* dense_b  = (const float*)d_in[9];
  const float* fc1_w    = (const float*)d_in[10];
  const float* fc1_b    = (const float*)d_in[11];
  const float* fc2_w    = (const float*)d_in[12];
  const float* fc2_b    = (const float*)d_in[13];
  const float* fln_g    = (const float*)d_in[14];
  const float* fln_b    = (const float*)d_in[15];
  const float* logits_w = (const float*)d_in[16];

  // workspace layout (160 MiB total)
  char* ws = (char*)d_ws;
  float* h        = (float*)(ws);                          // 16 MiB
  bf16*  xa       = (bf16*)(ws + (size_t)16 * (1 << 20));  // 32 MiB (S x FF bf16 max)
  float* attn_out = (float*)(ws + (size_t)48 * (1 << 20)); // 16 MiB
  float* U        = (float*)(ws + (size_t)64 * (1 << 20)); // 64 MiB union: qkv / mid / mlp_out
  bf16*  wb       = (bf16*)(ws + (size_t)128 * (1 << 20)); // 32 MiB (bf16 transposed weight)
  float* qkvb = U;
  float* mid = U;
  float* mlp_out = U;
  float* out = (float*)d_out;

  embed_k<<<S_, 256, 0, stream>>>(x, embed, h);
  for (int l = 0; l < 2; l++) {
    // attention branch
    ln_k<<<S_, 256, 0, stream>>>(h, ln1_g + l * H_, ln1_b + l * H_, xa);
    convT_k<<<dim3(TH_ / 32, H_ / 32), 256, 0, stream>>>(qkv_w + (size_t)l * H_ * TH_, wb, TH_, H_);
    gemm_bt<<<dim3(TH_ / 128, S_ / 128), 256, 0, stream>>>(xa, wb, qkv_b + l * TH_, qkvb, H_, TH_);
    rope_k<<<S_ * NH_ * 16 / 256, 256, 0, stream>>>(qkvb);
    fattn_k<<<(S_ / 64) * NH_, 256, 0, stream>>>(qkvb, xa);
    convT_k<<<dim3(H_ / 32, H_ / 32), 256, 0, stream>>>(dense_w + (size_t)l * H_ * H_, wb, H_, H_);
    gemm_bt<<<dim3(H_ / 128, S_ / 128), 256, 0, stream>>>(xa, wb, dense_b + l * H_, attn_out, H_, H_);
    // mlp branch (from pre-update h: parallel residual)
    ln_k<<<S_, 256, 0, stream>>>(h, ln2_g + l * H_, ln2_b + l * H_, xa);
    convT_k<<<dim3(FF_ / 32, H_ / 32), 256, 0, stream>>>(fc1_w + (size_t)l * H_ * FF_, wb, FF_, H_);
    gemm_bt<<<dim3(FF_ / 128, S_ / 128), 256, 0, stream>>>(xa, wb, fc1_b + l * FF_, mid, H_, FF_);
    gelu_k<<<S_ * FF_ / 4 / 256, 256, 0, stream>>>(mid, xa);
    convT_k<<<dim3(H_ / 32, FF_ / 32), 256, 0, stream>>>(fc2_w + (size_t)l * FF_ * H_, wb, H_, FF_);
    gemm_bt<<<dim3(H_ / 128, S_ / 128), 256, 0, stream>>>(xa, wb, fc2_b + l * H_, mlp_out, FF_, H_);
    resid_k<<<S_ * H_ / 4 / 256, 256, 0, stream>>>(h, attn_out, mlp_out);
  }
  // final LN + logits (chunked over V to bound wb size: 5 x 6400)
  ln_k<<<S_, 256, 0, stream>>>(h, fln_g, fln_b, xa);
  for (int c = 0; c < 5; c++) {
    convT_k<<<dim3(6400 / 32, H_ / 32), 256, 0, stream>>>(logits_w + c * 6400, wb, V_, H_);
    gemm_bt<<<dim3(6400 / 128, S_ / 128), 256, 0, stream>>>(xa, wb, nullptr, out + c * 6400, H_, V_);
  }
}